// Round 1
// baseline (348.212 us; speedup 1.0000x reference)
//
#include <hip/hip_runtime.h>

// Problem constants (fixed by the reference file)
#define NUM_GRAPHS 512
#define NPG        1024                 // nodes per graph
#define KSEL       512                  // ceil(NPG * 0.5)
#define NNODES     (NUM_GRAPHS * NPG)   // 524288
#define CFEAT      64
#define NEDGE      (16 * NNODES)        // 8388608

__device__ __forceinline__ unsigned rotl32(unsigned v, int d) {
  return (v << d) | (v >> (32 - d));
}

// JAX threefry2x32: 20 rounds, 5 key injections. Matches jax/_src/prng.py.
__device__ __forceinline__ void tf2x32(unsigned k0, unsigned k1,
                                       unsigned x0, unsigned x1,
                                       unsigned& o0, unsigned& o1) {
  unsigned ks2 = k0 ^ k1 ^ 0x1BD11BDAu;
  x0 += k0; x1 += k1;
  x0 += x1; x1 = rotl32(x1, 13); x1 ^= x0;
  x0 += x1; x1 = rotl32(x1, 15); x1 ^= x0;
  x0 += x1; x1 = rotl32(x1, 26); x1 ^= x0;
  x0 += x1; x1 = rotl32(x1, 6);  x1 ^= x0;
  x0 += k1; x1 += ks2 + 1u;
  x0 += x1; x1 = rotl32(x1, 17); x1 ^= x0;
  x0 += x1; x1 = rotl32(x1, 29); x1 ^= x0;
  x0 += x1; x1 = rotl32(x1, 16); x1 ^= x0;
  x0 += x1; x1 = rotl32(x1, 24); x1 ^= x0;
  x0 += ks2; x1 += k0 + 2u;
  x0 += x1; x1 = rotl32(x1, 13); x1 ^= x0;
  x0 += x1; x1 = rotl32(x1, 15); x1 ^= x0;
  x0 += x1; x1 = rotl32(x1, 26); x1 ^= x0;
  x0 += x1; x1 = rotl32(x1, 6);  x1 ^= x0;
  x0 += k0; x1 += k1 + 3u;
  x0 += x1; x1 = rotl32(x1, 17); x1 ^= x0;
  x0 += x1; x1 = rotl32(x1, 29); x1 ^= x0;
  x0 += x1; x1 = rotl32(x1, 16); x1 ^= x0;
  x0 += x1; x1 = rotl32(x1, 24); x1 ^= x0;
  x0 += k1; x1 += ks2 + 4u;
  x0 += x1; x1 = rotl32(x1, 13); x1 ^= x0;
  x0 += x1; x1 = rotl32(x1, 15); x1 ^= x0;
  x0 += x1; x1 = rotl32(x1, 26); x1 ^= x0;
  x0 += x1; x1 = rotl32(x1, 6);  x1 ^= x0;
  x0 += ks2; x1 += k0 + 5u;
  o0 = x0; o1 = x1;
}

// One block per graph: reproduce jax.random.permutation(kg, 1024)[:512],
// sort ids, write mask/perm/batch, gather x rows.
__global__ __launch_bounds__(256) void select_kernel(
    const float* __restrict__ x, float* __restrict__ out_x,
    float* __restrict__ out_b, float* __restrict__ out_p,
    int* __restrict__ mask) {
  __shared__ unsigned long long skeys[NPG];  // (sortkey<<32)|idx
  __shared__ int flags[NPG];
  __shared__ int ids[KSEL];
  __shared__ int ssum[256];

  const int g = blockIdx.x;
  const int tid = threadIdx.x;

  // key_g = threefry(root=(0,42), (0,g));  subkey = threefry(key_g, (0,1))
  unsigned kg0, kg1, sk0, sk1;
  tf2x32(0u, 42u, 0u, (unsigned)g, kg0, kg1);
  tf2x32(kg0, kg1, 0u, 1u, sk0, sk1);

  // sort_keys[i] = bits1 ^ bits2 of threefry(subkey, (0,i)) (partitionable path)
  for (int i = tid; i < NPG; i += 256) {
    unsigned b1, b2;
    tf2x32(sk0, sk1, 0u, (unsigned)i, b1, b2);
    unsigned key = b1 ^ b2;
    skeys[i] = ((unsigned long long)key << 32) | (unsigned)i;
    flags[i] = 0;
  }
  __syncthreads();

  // bitonic sort ascending (stable via idx in low bits == lax stable sort)
  for (int k = 2; k <= NPG; k <<= 1) {
    for (int j = k >> 1; j > 0; j >>= 1) {
      for (int i = tid; i < NPG; i += 256) {
        int ixj = i ^ j;
        if (ixj > i) {
          unsigned long long a = skeys[i], b = skeys[ixj];
          bool up = ((i & k) == 0);
          if ((a > b) == up) { skeys[i] = b; skeys[ixj] = a; }
        }
      }
      __syncthreads();
    }
  }

  // membership of the k_sel smallest
  for (int t = tid; t < KSEL; t += 256) {
    flags[(int)(skeys[t] & (unsigned long long)(NPG - 1))] = 1;
  }
  __syncthreads();

  // exclusive prefix scan over 1024 flags (4 per thread + block scan)
  int i4 = tid * 4;
  int f0 = flags[i4], f1 = flags[i4 + 1], f2 = flags[i4 + 2], f3 = flags[i4 + 3];
  int local = f0 + f1 + f2 + f3;
  ssum[tid] = local;
  __syncthreads();
  for (int off = 1; off < 256; off <<= 1) {
    int v = (tid >= off) ? ssum[tid - off] : 0;
    __syncthreads();
    ssum[tid] += v;
    __syncthreads();
  }
  int pos = ssum[tid] - local;  // exclusive prefix

  int fj[4] = {f0, f1, f2, f3};
#pragma unroll
  for (int jj = 0; jj < 4; ++jj) {
    int i = i4 + jj;
    int node = g * NPG + i;
    int sel = fj[jj];
    int p = g * KSEL + pos;
    mask[node] = sel ? p : -1;
    if (sel) {
      ids[pos] = i;
      out_b[p] = (float)g;
      out_p[p] = (float)node;
    }
    pos += sel;
  }
  __syncthreads();

  // gather selected rows of x: KSEL rows x 16 float4
  const float4* xs = (const float4*)x;
  float4* xd = (float4*)out_x;
  for (int t = tid; t < KSEL * 16; t += 256) {
    int r = t >> 4;
    int c = t & 15;
    int id = ids[r];
    xd[(size_t)(g * KSEL + r) * 16 + c] = xs[(size_t)(g * NPG + id) * 16 + c];
  }
}

// Edge relabel/filter: 4 edges per thread, int4/float4 vectorized.
__global__ __launch_bounds__(256) void edge_kernel(
    const int* __restrict__ ei, const int* __restrict__ mask,
    float* __restrict__ out_e) {
  int t = blockIdx.x * 256 + threadIdx.x;
  int base = t * 4;  // NEDGE divisible by 4; grid sized exactly
  int4 s = *(const int4*)(ei + base);
  int4 d = *(const int4*)(ei + (size_t)NEDGE + base);
  int rs0 = mask[s.x], rs1 = mask[s.y], rs2 = mask[s.z], rs3 = mask[s.w];
  int cs0 = mask[d.x], cs1 = mask[d.y], cs2 = mask[d.z], cs3 = mask[d.w];
  float4 orow, ocol;
  bool k0 = (rs0 >= 0) && (cs0 >= 0);
  bool k1 = (rs1 >= 0) && (cs1 >= 0);
  bool k2 = (rs2 >= 0) && (cs2 >= 0);
  bool k3 = (rs3 >= 0) && (cs3 >= 0);
  orow.x = k0 ? (float)rs0 : -1.0f;  ocol.x = k0 ? (float)cs0 : -1.0f;
  orow.y = k1 ? (float)rs1 : -1.0f;  ocol.y = k1 ? (float)cs1 : -1.0f;
  orow.z = k2 ? (float)rs2 : -1.0f;  ocol.z = k2 ? (float)cs2 : -1.0f;
  orow.w = k3 ? (float)rs3 : -1.0f;  ocol.w = k3 ? (float)cs3 : -1.0f;
  *(float4*)(out_e + base) = orow;
  *(float4*)(out_e + (size_t)NEDGE + base) = ocol;
}

extern "C" void kernel_launch(void* const* d_in, const int* in_sizes, int n_in,
                              void* d_out, int out_size, void* d_ws, size_t ws_size,
                              hipStream_t stream) {
  const float* x  = (const float*)d_in[0];
  const int*   ei = (const int*)d_in[1];   // harness stores integer inputs as int32
  // d_in[2] (batch) unused: batch_sel[p] == p / KSEL by construction.

  float* out   = (float*)d_out;
  float* out_x = out;                                            // 16777216
  float* out_e = out + (size_t)NUM_GRAPHS * KSEL * CFEAT;        // 16777216
  float* out_b = out_e + 2 * (size_t)NEDGE;                      // 262144
  float* out_p = out_b + (size_t)NUM_GRAPHS * KSEL;              // 262144

  int* mask = (int*)d_ws;  // NNODES int32 = 2 MB scratch

  select_kernel<<<NUM_GRAPHS, 256, 0, stream>>>(x, out_x, out_b, out_p, mask);
  edge_kernel<<<NEDGE / 1024, 256, 0, stream>>>(ei, mask, out_e);
}

// Round 2
// 339.412 us; speedup vs baseline: 1.0259x; 1.0259x over previous
//
#include <hip/hip_runtime.h>

#define NUM_GRAPHS 512
#define NPG        1024
#define KSEL       512
#define NNODES     (NUM_GRAPHS * NPG)   // 524288
#define CFEAT      64
#define NEDGE      (16 * NNODES)        // 8388608

typedef int   int4v   __attribute__((ext_vector_type(4)));
typedef float float4v __attribute__((ext_vector_type(4)));

__device__ __forceinline__ unsigned rotl32(unsigned v, int d) {
  return (v << d) | (v >> (32 - d));
}

// JAX threefry2x32: 20 rounds, 5 key injections.
__device__ __forceinline__ void tf2x32(unsigned k0, unsigned k1,
                                       unsigned x0, unsigned x1,
                                       unsigned& o0, unsigned& o1) {
  unsigned ks2 = k0 ^ k1 ^ 0x1BD11BDAu;
  x0 += k0; x1 += k1;
  x0 += x1; x1 = rotl32(x1, 13); x1 ^= x0;
  x0 += x1; x1 = rotl32(x1, 15); x1 ^= x0;
  x0 += x1; x1 = rotl32(x1, 26); x1 ^= x0;
  x0 += x1; x1 = rotl32(x1, 6);  x1 ^= x0;
  x0 += k1; x1 += ks2 + 1u;
  x0 += x1; x1 = rotl32(x1, 17); x1 ^= x0;
  x0 += x1; x1 = rotl32(x1, 29); x1 ^= x0;
  x0 += x1; x1 = rotl32(x1, 16); x1 ^= x0;
  x0 += x1; x1 = rotl32(x1, 24); x1 ^= x0;
  x0 += ks2; x1 += k0 + 2u;
  x0 += x1; x1 = rotl32(x1, 13); x1 ^= x0;
  x0 += x1; x1 = rotl32(x1, 15); x1 ^= x0;
  x0 += x1; x1 = rotl32(x1, 26); x1 ^= x0;
  x0 += x1; x1 = rotl32(x1, 6);  x1 ^= x0;
  x0 += k0; x1 += k1 + 3u;
  x0 += x1; x1 = rotl32(x1, 17); x1 ^= x0;
  x0 += x1; x1 = rotl32(x1, 29); x1 ^= x0;
  x0 += x1; x1 = rotl32(x1, 16); x1 ^= x0;
  x0 += x1; x1 = rotl32(x1, 24); x1 ^= x0;
  x0 += k1; x1 += ks2 + 4u;
  x0 += x1; x1 = rotl32(x1, 13); x1 ^= x0;
  x0 += x1; x1 = rotl32(x1, 15); x1 ^= x0;
  x0 += x1; x1 = rotl32(x1, 26); x1 ^= x0;
  x0 += x1; x1 = rotl32(x1, 6);  x1 ^= x0;
  x0 += ks2; x1 += k0 + 5u;
  o0 = x0; o1 = x1;
}

// One block (512 thr) per graph: jax.random.permutation(kg,1024)[:512] membership,
// write mask16/perm/batch, gather x rows (nt streaming).
__global__ __launch_bounds__(512) void select_kernel(
    const float* __restrict__ x, float* __restrict__ out_x,
    float* __restrict__ out_b, float* __restrict__ out_p,
    unsigned short* __restrict__ mask) {
  __shared__ unsigned long long skeys[NPG];  // (sortkey<<32)|idx
  __shared__ int flags[NPG];
  __shared__ short ids[KSEL];
  __shared__ int ssum[512];

  const int g = blockIdx.x;
  const int tid = threadIdx.x;

  unsigned kg0, kg1, sk0, sk1;
  tf2x32(0u, 42u, 0u, (unsigned)g, kg0, kg1);
  tf2x32(kg0, kg1, 0u, 1u, sk0, sk1);

  for (int i = tid; i < NPG; i += 512) {
    unsigned b1, b2;
    tf2x32(sk0, sk1, 0u, (unsigned)i, b1, b2);
    unsigned key = b1 ^ b2;
    skeys[i] = ((unsigned long long)key << 32) | (unsigned)i;
    flags[i] = 0;
  }
  __syncthreads();

  // bitonic sort ascending over 1024 u64; 512 active compares per stage
  for (int k = 2; k <= NPG; k <<= 1) {
    for (int j = k >> 1; j > 0; j >>= 1) {
      for (int i = tid; i < NPG; i += 512) {
        int ixj = i ^ j;
        if (ixj > i) {
          unsigned long long a = skeys[i], b = skeys[ixj];
          bool up = ((i & k) == 0);
          if ((a > b) == up) { skeys[i] = b; skeys[ixj] = a; }
        }
      }
      __syncthreads();
    }
  }

  // membership of the KSEL smallest
  if (tid < KSEL) flags[(int)(skeys[tid] & (unsigned long long)(NPG - 1))] = 1;
  __syncthreads();

  // exclusive prefix scan over 1024 flags (2/thread)
  int i2 = tid * 2;
  int f0 = flags[i2], f1 = flags[i2 + 1];
  int local = f0 + f1;
  ssum[tid] = local;
  __syncthreads();
  for (int off = 1; off < 512; off <<= 1) {
    int v = (tid >= off) ? ssum[tid - off] : 0;
    __syncthreads();
    ssum[tid] += v;
    __syncthreads();
  }
  int pos = ssum[tid] - local;

  {
    int i = i2;
    int node = g * NPG + i;
    unsigned short m0 = f0 ? (unsigned short)pos : (unsigned short)0xFFFF;
    if (f0) {
      ids[pos] = (short)i;
      out_b[g * KSEL + pos] = (float)g;
      out_p[g * KSEL + pos] = (float)node;
      pos++;
    }
    int i_1 = i2 + 1;
    unsigned short m1 = f1 ? (unsigned short)pos : (unsigned short)0xFFFF;
    if (f1) {
      ids[pos] = (short)i_1;
      out_b[g * KSEL + pos] = (float)g;
      out_p[g * KSEL + pos] = (float)(node + 1);
    }
    // coalesced paired u16 store
    unsigned packed = (unsigned)m0 | ((unsigned)m1 << 16);
    *((unsigned*)(mask + (size_t)g * NPG + i2)) = packed;
  }
  __syncthreads();

  // gather selected rows of x: KSEL rows x 16 float4 (nt streaming both ways)
  const float4v* xs = (const float4v*)x;
  float4v* xd = (float4v*)out_x;
  for (int t = tid; t < KSEL * 16; t += 512) {
    int r = t >> 4;
    int c = t & 15;
    int id = ids[r];
    float4v v = __builtin_nontemporal_load(&xs[(size_t)(g * NPG + id) * 16 + c]);
    __builtin_nontemporal_store(v, &xd[(size_t)(g * KSEL + r) * 16 + c]);
  }
}

// Edge relabel/filter: 4 edges/thread; nt streaming for ei/out, cached u16 mask.
__global__ __launch_bounds__(256) void edge_kernel(
    const int* __restrict__ ei, const unsigned short* __restrict__ mask,
    float* __restrict__ out_e) {
  int t = blockIdx.x * 256 + threadIdx.x;
  int base = t * 4;
  int4v s = __builtin_nontemporal_load((const int4v*)(ei + base));
  int4v d = __builtin_nontemporal_load((const int4v*)(ei + (size_t)NEDGE + base));
  unsigned rs0 = mask[s.x], rs1 = mask[s.y], rs2 = mask[s.z], rs3 = mask[s.w];
  unsigned cs0 = mask[d.x], cs1 = mask[d.y], cs2 = mask[d.z], cs3 = mask[d.w];
  float4v orow, ocol;
  bool k0 = (rs0 != 0xFFFFu) && (cs0 != 0xFFFFu);
  bool k1 = (rs1 != 0xFFFFu) && (cs1 != 0xFFFFu);
  bool k2 = (rs2 != 0xFFFFu) && (cs2 != 0xFFFFu);
  bool k3 = (rs3 != 0xFFFFu) && (cs3 != 0xFFFFu);
  // global row id = (node>>10)*512 + local = ((node & ~1023) >> 1) + local
  orow.x = k0 ? (float)(((s.x & ~1023) >> 1) + (int)rs0) : -1.0f;
  ocol.x = k0 ? (float)(((d.x & ~1023) >> 1) + (int)cs0) : -1.0f;
  orow.y = k1 ? (float)(((s.y & ~1023) >> 1) + (int)rs1) : -1.0f;
  ocol.y = k1 ? (float)(((d.y & ~1023) >> 1) + (int)cs1) : -1.0f;
  orow.z = k2 ? (float)(((s.z & ~1023) >> 1) + (int)rs2) : -1.0f;
  ocol.z = k2 ? (float)(((d.z & ~1023) >> 1) + (int)cs2) : -1.0f;
  orow.w = k3 ? (float)(((s.w & ~1023) >> 1) + (int)rs3) : -1.0f;
  ocol.w = k3 ? (float)(((d.w & ~1023) >> 1) + (int)cs3) : -1.0f;
  __builtin_nontemporal_store(orow, (float4v*)(out_e + base));
  __builtin_nontemporal_store(ocol, (float4v*)(out_e + (size_t)NEDGE + base));
}

extern "C" void kernel_launch(void* const* d_in, const int* in_sizes, int n_in,
                              void* d_out, int out_size, void* d_ws, size_t ws_size,
                              hipStream_t stream) {
  const float* x  = (const float*)d_in[0];
  const int*   ei = (const int*)d_in[1];

  float* out   = (float*)d_out;
  float* out_x = out;                                            // 16777216
  float* out_e = out + (size_t)NUM_GRAPHS * KSEL * CFEAT;        // 16777216
  float* out_b = out_e + 2 * (size_t)NEDGE;                      // 262144
  float* out_p = out_b + (size_t)NUM_GRAPHS * KSEL;              // 262144

  unsigned short* mask = (unsigned short*)d_ws;  // NNODES u16 = 1 MB

  select_kernel<<<NUM_GRAPHS, 512, 0, stream>>>(x, out_x, out_b, out_p, mask);
  edge_kernel<<<NEDGE / 1024, 256, 0, stream>>>(ei, mask, out_e);
}

// Round 3
// 327.458 us; speedup vs baseline: 1.0634x; 1.0365x over previous
//
#include <hip/hip_runtime.h>

#define NUM_GRAPHS 512
#define NPG        1024
#define KSEL       512
#define NNODES     (NUM_GRAPHS * NPG)   // 524288
#define CFEAT      64
#define NEDGE      (16 * NNODES)        // 8388608

typedef int   int4v   __attribute__((ext_vector_type(4)));
typedef float float4v __attribute__((ext_vector_type(4)));

__device__ __forceinline__ unsigned rotl32(unsigned v, int d) {
  return (v << d) | (v >> (32 - d));
}

// JAX threefry2x32: 20 rounds, 5 key injections.
__device__ __forceinline__ void tf2x32(unsigned k0, unsigned k1,
                                       unsigned x0, unsigned x1,
                                       unsigned& o0, unsigned& o1) {
  unsigned ks2 = k0 ^ k1 ^ 0x1BD11BDAu;
  x0 += k0; x1 += k1;
  x0 += x1; x1 = rotl32(x1, 13); x1 ^= x0;
  x0 += x1; x1 = rotl32(x1, 15); x1 ^= x0;
  x0 += x1; x1 = rotl32(x1, 26); x1 ^= x0;
  x0 += x1; x1 = rotl32(x1, 6);  x1 ^= x0;
  x0 += k1; x1 += ks2 + 1u;
  x0 += x1; x1 = rotl32(x1, 17); x1 ^= x0;
  x0 += x1; x1 = rotl32(x1, 29); x1 ^= x0;
  x0 += x1; x1 = rotl32(x1, 16); x1 ^= x0;
  x0 += x1; x1 = rotl32(x1, 24); x1 ^= x0;
  x0 += ks2; x1 += k0 + 2u;
  x0 += x1; x1 = rotl32(x1, 13); x1 ^= x0;
  x0 += x1; x1 = rotl32(x1, 15); x1 ^= x0;
  x0 += x1; x1 = rotl32(x1, 26); x1 ^= x0;
  x0 += x1; x1 = rotl32(x1, 6);  x1 ^= x0;
  x0 += k0; x1 += k1 + 3u;
  x0 += x1; x1 = rotl32(x1, 17); x1 ^= x0;
  x0 += x1; x1 = rotl32(x1, 29); x1 ^= x0;
  x0 += x1; x1 = rotl32(x1, 16); x1 ^= x0;
  x0 += x1; x1 = rotl32(x1, 24); x1 ^= x0;
  x0 += k1; x1 += ks2 + 4u;
  x0 += x1; x1 = rotl32(x1, 13); x1 ^= x0;
  x0 += x1; x1 = rotl32(x1, 15); x1 ^= x0;
  x0 += x1; x1 = rotl32(x1, 26); x1 ^= x0;
  x0 += x1; x1 = rotl32(x1, 6);  x1 ^= x0;
  x0 += ks2; x1 += k0 + 5u;
  o0 = x0; o1 = x1;
}

// One block (512 thr) per graph: jax.random.permutation(kg,1024)[:512] membership,
// write mask16/perm/batch, gather x rows (nt streaming).
__global__ __launch_bounds__(512) void select_kernel(
    const float* __restrict__ x, float* __restrict__ out_x,
    float* __restrict__ out_b, float* __restrict__ out_p,
    unsigned short* __restrict__ mask) {
  __shared__ unsigned long long skeys[NPG];  // (sortkey<<32)|idx
  __shared__ int flags[NPG];
  __shared__ short ids[KSEL];
  __shared__ int ssum[512];

  const int g = blockIdx.x;
  const int tid = threadIdx.x;

  unsigned kg0, kg1, sk0, sk1;
  tf2x32(0u, 42u, 0u, (unsigned)g, kg0, kg1);
  tf2x32(kg0, kg1, 0u, 1u, sk0, sk1);

  for (int i = tid; i < NPG; i += 512) {
    unsigned b1, b2;
    tf2x32(sk0, sk1, 0u, (unsigned)i, b1, b2);
    unsigned key = b1 ^ b2;
    skeys[i] = ((unsigned long long)key << 32) | (unsigned)i;
    flags[i] = 0;
  }
  __syncthreads();

  // bitonic sort ascending over 1024 u64; 512 active compares per stage
  for (int k = 2; k <= NPG; k <<= 1) {
    for (int j = k >> 1; j > 0; j >>= 1) {
      for (int i = tid; i < NPG; i += 512) {
        int ixj = i ^ j;
        if (ixj > i) {
          unsigned long long a = skeys[i], b = skeys[ixj];
          bool up = ((i & k) == 0);
          if ((a > b) == up) { skeys[i] = b; skeys[ixj] = a; }
        }
      }
      __syncthreads();
    }
  }

  // membership of the KSEL smallest
  if (tid < KSEL) flags[(int)(skeys[tid] & (unsigned long long)(NPG - 1))] = 1;
  __syncthreads();

  // exclusive prefix scan over 1024 flags (2/thread)
  int i2 = tid * 2;
  int f0 = flags[i2], f1 = flags[i2 + 1];
  int local = f0 + f1;
  ssum[tid] = local;
  __syncthreads();
  for (int off = 1; off < 512; off <<= 1) {
    int v = (tid >= off) ? ssum[tid - off] : 0;
    __syncthreads();
    ssum[tid] += v;
    __syncthreads();
  }
  int pos = ssum[tid] - local;

  {
    int i = i2;
    int node = g * NPG + i;
    unsigned short m0 = f0 ? (unsigned short)pos : (unsigned short)0xFFFF;
    if (f0) {
      ids[pos] = (short)i;
      out_b[g * KSEL + pos] = (float)g;
      out_p[g * KSEL + pos] = (float)node;
      pos++;
    }
    int i_1 = i2 + 1;
    unsigned short m1 = f1 ? (unsigned short)pos : (unsigned short)0xFFFF;
    if (f1) {
      ids[pos] = (short)i_1;
      out_b[g * KSEL + pos] = (float)g;
      out_p[g * KSEL + pos] = (float)(node + 1);
    }
    // coalesced paired u16 store
    unsigned packed = (unsigned)m0 | ((unsigned)m1 << 16);
    *((unsigned*)(mask + (size_t)g * NPG + i2)) = packed;
  }
  __syncthreads();

  // gather selected rows of x: KSEL rows x 16 float4 (nt streaming both ways)
  const float4v* xs = (const float4v*)x;
  float4v* xd = (float4v*)out_x;
  for (int t = tid; t < KSEL * 16; t += 512) {
    int r = t >> 4;
    int c = t & 15;
    int id = ids[r];
    float4v v = __builtin_nontemporal_load(&xs[(size_t)(g * NPG + id) * 16 + c]);
    __builtin_nontemporal_store(v, &xd[(size_t)(g * KSEL + r) * 16 + c]);
  }
}

// Edge relabel/filter: 8 edges/thread.
//  - mask lookups use agent-scope relaxed loads -> glc/sc0, bypass L1 miss path
//  - col lookup exec-masked off when row already invalid (~25% fewer lookups)
//  - nt streaming for ei reads / out writes
__global__ __launch_bounds__(256) void edge_kernel(
    const int* __restrict__ ei, const unsigned short* __restrict__ mask,
    float* __restrict__ out_e) {
  const int t = blockIdx.x * 256 + threadIdx.x;
  const int base = t * 8;

  int4v s0 = __builtin_nontemporal_load((const int4v*)(ei + base));
  int4v s1 = __builtin_nontemporal_load((const int4v*)(ei + base + 4));
  int4v d0 = __builtin_nontemporal_load((const int4v*)(ei + (size_t)NEDGE + base));
  int4v d1 = __builtin_nontemporal_load((const int4v*)(ei + (size_t)NEDGE + base + 4));

  int src[8] = {s0.x, s0.y, s0.z, s0.w, s1.x, s1.y, s1.z, s1.w};
  int dst[8] = {d0.x, d0.y, d0.z, d0.w, d1.x, d1.y, d1.z, d1.w};

  unsigned short rs[8];
#pragma unroll
  for (int j = 0; j < 8; ++j) {
    rs[j] = __hip_atomic_load(&mask[src[j]], __ATOMIC_RELAXED,
                              __HIP_MEMORY_SCOPE_AGENT);
  }

  unsigned short cs[8];
#pragma unroll
  for (int j = 0; j < 8; ++j) {
    cs[j] = 0xFFFFu;
    if (rs[j] != 0xFFFFu) {
      cs[j] = __hip_atomic_load(&mask[dst[j]], __ATOMIC_RELAXED,
                                __HIP_MEMORY_SCOPE_AGENT);
    }
  }

  float orow[8], ocol[8];
#pragma unroll
  for (int j = 0; j < 8; ++j) {
    bool k = (rs[j] != 0xFFFFu) && (cs[j] != 0xFFFFu);
    // global row id = (node>>10)*512 + local = ((node & ~1023) >> 1) + local
    orow[j] = k ? (float)(((src[j] & ~1023) >> 1) + (int)rs[j]) : -1.0f;
    ocol[j] = k ? (float)(((dst[j] & ~1023) >> 1) + (int)cs[j]) : -1.0f;
  }

  float4v r0 = {orow[0], orow[1], orow[2], orow[3]};
  float4v r1 = {orow[4], orow[5], orow[6], orow[7]};
  float4v c0 = {ocol[0], ocol[1], ocol[2], ocol[3]};
  float4v c1 = {ocol[4], ocol[5], ocol[6], ocol[7]};
  __builtin_nontemporal_store(r0, (float4v*)(out_e + base));
  __builtin_nontemporal_store(r1, (float4v*)(out_e + base + 4));
  __builtin_nontemporal_store(c0, (float4v*)(out_e + (size_t)NEDGE + base));
  __builtin_nontemporal_store(c1, (float4v*)(out_e + (size_t)NEDGE + base + 4));
}

extern "C" void kernel_launch(void* const* d_in, const int* in_sizes, int n_in,
                              void* d_out, int out_size, void* d_ws, size_t ws_size,
                              hipStream_t stream) {
  const float* x  = (const float*)d_in[0];
  const int*   ei = (const int*)d_in[1];

  float* out   = (float*)d_out;
  float* out_x = out;                                            // 16777216
  float* out_e = out + (size_t)NUM_GRAPHS * KSEL * CFEAT;        // 16777216
  float* out_b = out_e + 2 * (size_t)NEDGE;                      // 262144
  float* out_p = out_b + (size_t)NUM_GRAPHS * KSEL;              // 262144

  unsigned short* mask = (unsigned short*)d_ws;  // NNODES u16 = 1 MB

  select_kernel<<<NUM_GRAPHS, 512, 0, stream>>>(x, out_x, out_b, out_p, mask);
  edge_kernel<<<NEDGE / 2048, 256, 0, stream>>>(ei, mask, out_e);
}

// Round 4
// 301.840 us; speedup vs baseline: 1.1536x; 1.0849x over previous
//
#include <hip/hip_runtime.h>

#define NUM_GRAPHS 512
#define NPG        1024
#define KSEL       512
#define NNODES     (NUM_GRAPHS * NPG)   // 524288
#define CFEAT      64
#define NEDGE      (16 * NNODES)        // 8388608
#define NWORDS     (NUM_GRAPHS * 32)    // 16384 table entries (u64 each)

typedef int   int4v   __attribute__((ext_vector_type(4)));
typedef float float4v __attribute__((ext_vector_type(4)));

__device__ __forceinline__ unsigned rotl32(unsigned v, int d) {
  return (v << d) | (v >> (32 - d));
}

// JAX threefry2x32: 20 rounds, 5 key injections.
__device__ __forceinline__ void tf2x32(unsigned k0, unsigned k1,
                                       unsigned x0, unsigned x1,
                                       unsigned& o0, unsigned& o1) {
  unsigned ks2 = k0 ^ k1 ^ 0x1BD11BDAu;
  x0 += k0; x1 += k1;
  x0 += x1; x1 = rotl32(x1, 13); x1 ^= x0;
  x0 += x1; x1 = rotl32(x1, 15); x1 ^= x0;
  x0 += x1; x1 = rotl32(x1, 26); x1 ^= x0;
  x0 += x1; x1 = rotl32(x1, 6);  x1 ^= x0;
  x0 += k1; x1 += ks2 + 1u;
  x0 += x1; x1 = rotl32(x1, 17); x1 ^= x0;
  x0 += x1; x1 = rotl32(x1, 29); x1 ^= x0;
  x0 += x1; x1 = rotl32(x1, 16); x1 ^= x0;
  x0 += x1; x1 = rotl32(x1, 24); x1 ^= x0;
  x0 += ks2; x1 += k0 + 2u;
  x0 += x1; x1 = rotl32(x1, 13); x1 ^= x0;
  x0 += x1; x1 = rotl32(x1, 15); x1 ^= x0;
  x0 += x1; x1 = rotl32(x1, 26); x1 ^= x0;
  x0 += x1; x1 = rotl32(x1, 6);  x1 ^= x0;
  x0 += k0; x1 += k1 + 3u;
  x0 += x1; x1 = rotl32(x1, 17); x1 ^= x0;
  x0 += x1; x1 = rotl32(x1, 29); x1 ^= x0;
  x0 += x1; x1 = rotl32(x1, 16); x1 ^= x0;
  x0 += x1; x1 = rotl32(x1, 24); x1 ^= x0;
  x0 += k1; x1 += ks2 + 4u;
  x0 += x1; x1 = rotl32(x1, 13); x1 ^= x0;
  x0 += x1; x1 = rotl32(x1, 15); x1 ^= x0;
  x0 += x1; x1 = rotl32(x1, 26); x1 ^= x0;
  x0 += x1; x1 = rotl32(x1, 6);  x1 ^= x0;
  x0 += ks2; x1 += k0 + 5u;
  o0 = x0; o1 = x1;
}

// One block (512 thr) per graph: permutation(kg,1024)[:512] membership,
// emit: packed (bitmap,base) table entry per 32 nodes, selected ids, batch, perm.
__global__ __launch_bounds__(512) void select_kernel(
    float* __restrict__ out_b, float* __restrict__ out_p,
    unsigned long long* __restrict__ tab, unsigned short* __restrict__ ids_ws) {
  __shared__ unsigned long long skeys[NPG];
  __shared__ int flags[NPG];
  __shared__ short ids[KSEL];
  __shared__ int ssum[512];

  const int g = blockIdx.x;
  const int tid = threadIdx.x;

  unsigned kg0, kg1, sk0, sk1;
  tf2x32(0u, 42u, 0u, (unsigned)g, kg0, kg1);
  tf2x32(kg0, kg1, 0u, 1u, sk0, sk1);

  for (int i = tid; i < NPG; i += 512) {
    unsigned b1, b2;
    tf2x32(sk0, sk1, 0u, (unsigned)i, b1, b2);
    unsigned key = b1 ^ b2;
    skeys[i] = ((unsigned long long)key << 32) | (unsigned)i;
    flags[i] = 0;
  }
  __syncthreads();

  // bitonic sort ascending over 1024 u64
  for (int k = 2; k <= NPG; k <<= 1) {
    for (int j = k >> 1; j > 0; j >>= 1) {
      for (int i = tid; i < NPG; i += 512) {
        int ixj = i ^ j;
        if (ixj > i) {
          unsigned long long a = skeys[i], b = skeys[ixj];
          bool up = ((i & k) == 0);
          if ((a > b) == up) { skeys[i] = b; skeys[ixj] = a; }
        }
      }
      __syncthreads();
    }
  }

  if (tid < KSEL) flags[(int)(skeys[tid] & (unsigned long long)(NPG - 1))] = 1;
  __syncthreads();

  // exclusive prefix scan over 1024 flags (2/thread)
  int i2 = tid * 2;
  int f0 = flags[i2], f1 = flags[i2 + 1];
  int local = f0 + f1;
  ssum[tid] = local;
  __syncthreads();
  for (int off = 1; off < 512; off <<= 1) {
    int v = (tid >= off) ? ssum[tid - off] : 0;
    __syncthreads();
    ssum[tid] += v;
    __syncthreads();
  }
  int pos = ssum[tid] - local;

  // scatter ids / batch / perm
  {
    int i = i2;
    int node = g * NPG + i;
    if (f0) {
      ids[pos] = (short)i;
      out_b[g * KSEL + pos] = (float)g;
      out_p[g * KSEL + pos] = (float)node;
      pos++;
    }
    if (f1) {
      ids[pos] = (short)(i + 1);
      out_b[g * KSEL + pos] = (float)g;
      out_p[g * KSEL + pos] = (float)(node + 1);
    }
  }

  // packed lookup table: per 32 nodes, bitmap word + exclusive base
  if (tid < 32) {
    unsigned w = 0;
#pragma unroll
    for (int j = 0; j < 32; ++j) w |= ((unsigned)(flags[tid * 32 + j] & 1)) << j;
    unsigned base = (tid == 0) ? 0u : (unsigned)ssum[tid * 16 - 1];
    tab[g * 32 + tid] = (unsigned long long)w |
                        ((unsigned long long)base << 32);
  }
  __syncthreads();

  if (tid < KSEL) ids_ws[g * KSEL + tid] = (unsigned short)ids[tid];
}

// Fused gather + edge filter. 256 blocks x 1024 thr, 1 block/CU.
// The full (bitmap,base) table lives in LDS: every endpoint lookup is one
// scattered ds_read_b64 + popcount instead of an L2 round-trip.
__global__ __launch_bounds__(1024) void fused_kernel(
    const float* __restrict__ x, const int* __restrict__ ei,
    const unsigned long long* __restrict__ tab,
    const unsigned short* __restrict__ ids_ws,
    float* __restrict__ out_x, float* __restrict__ out_e) {
  __shared__ unsigned long long ltab[NWORDS];   // 128 KB
  __shared__ unsigned short lids[1024];         // this block's gather rows

  const int tid = threadIdx.x;
  const int blk = blockIdx.x;

  // stage table (16 u64 per thread, coalesced)
#pragma unroll
  for (int k = 0; k < NWORDS / 1024; ++k) {
    ltab[k * 1024 + tid] = tab[k * 1024 + tid];
  }
  // this block's 1024 gather rows
  {
    const int row0 = blk * 1024;
    if (tid < 512) {
      ((unsigned*)lids)[tid] = ((const unsigned*)(ids_ws + row0))[tid];
    }
  }
  __syncthreads();

  // phase B: gather x rows. rows [blk*1024, blk*1024+1024), 16 float4/row
  {
    const float4v* xs = (const float4v*)x;
    float4v* xd = (float4v*)out_x;
    const int row0 = blk * 1024;
#pragma unroll
    for (int k = 0; k < 16; ++k) {
      int t = k * 1024 + tid;
      int r = t >> 4;           // local row 0..1023
      int c = t & 15;
      int row = row0 + r;       // global out row
      int g = row >> 9;         // graph
      int id = lids[r];
      float4v v = __builtin_nontemporal_load(
          &xs[((size_t)g * NPG + id) * 16 + c]);
      __builtin_nontemporal_store(v, &xd[(size_t)row * 16 + c]);
    }
  }

  // phase C: edges. 32 per thread, 4 chunks of 8.
#pragma unroll
  for (int k = 0; k < 4; ++k) {
    const int base = (((k * 256 + blk) * 1024) + tid) * 8;
    int4v s0 = __builtin_nontemporal_load((const int4v*)(ei + base));
    int4v s1 = __builtin_nontemporal_load((const int4v*)(ei + base + 4));
    int4v d0 = __builtin_nontemporal_load((const int4v*)(ei + (size_t)NEDGE + base));
    int4v d1 = __builtin_nontemporal_load((const int4v*)(ei + (size_t)NEDGE + base + 4));

    int src[8] = {s0.x, s0.y, s0.z, s0.w, s1.x, s1.y, s1.z, s1.w};
    int dst[8] = {d0.x, d0.y, d0.z, d0.w, d1.x, d1.y, d1.z, d1.w};

    int rrow[8], rcol[8];
#pragma unroll
    for (int j = 0; j < 8; ++j) {
      unsigned long long es = ltab[src[j] >> 5];
      unsigned long long ed = ltab[dst[j] >> 5];
      unsigned ws = (unsigned)es, wd = (unsigned)ed;
      int shs = src[j] & 31, shd = dst[j] & 31;
      bool sels = (ws >> shs) & 1u;
      bool seld = (wd >> shd) & 1u;
      int poss = (int)(es >> 32) + __popc(ws & ((1u << shs) - 1u));
      int posd = (int)(ed >> 32) + __popc(wd & ((1u << shd) - 1u));
      bool keep = sels && seld;
      rrow[j] = keep ? (((src[j] & ~1023) >> 1) + poss) : -1;
      rcol[j] = keep ? (((dst[j] & ~1023) >> 1) + posd) : -1;
    }

    float4v r0 = {(float)rrow[0], (float)rrow[1], (float)rrow[2], (float)rrow[3]};
    float4v r1 = {(float)rrow[4], (float)rrow[5], (float)rrow[6], (float)rrow[7]};
    float4v c0 = {(float)rcol[0], (float)rcol[1], (float)rcol[2], (float)rcol[3]};
    float4v c1 = {(float)rcol[4], (float)rcol[5], (float)rcol[6], (float)rcol[7]};
    __builtin_nontemporal_store(r0, (float4v*)(out_e + base));
    __builtin_nontemporal_store(r1, (float4v*)(out_e + base + 4));
    __builtin_nontemporal_store(c0, (float4v*)(out_e + (size_t)NEDGE + base));
    __builtin_nontemporal_store(c1, (float4v*)(out_e + (size_t)NEDGE + base + 4));
  }
}

extern "C" void kernel_launch(void* const* d_in, const int* in_sizes, int n_in,
                              void* d_out, int out_size, void* d_ws, size_t ws_size,
                              hipStream_t stream) {
  const float* x  = (const float*)d_in[0];
  const int*   ei = (const int*)d_in[1];

  float* out   = (float*)d_out;
  float* out_x = out;                                            // 16777216
  float* out_e = out + (size_t)NUM_GRAPHS * KSEL * CFEAT;        // 16777216
  float* out_b = out_e + 2 * (size_t)NEDGE;                      // 262144
  float* out_p = out_b + (size_t)NUM_GRAPHS * KSEL;              // 262144

  // d_ws layout: [0,128K) u64 table; [128K, 128K+512K) u16 ids
  unsigned long long* tab = (unsigned long long*)d_ws;
  unsigned short* ids_ws = (unsigned short*)((char*)d_ws + NWORDS * 8);

  select_kernel<<<NUM_GRAPHS, 512, 0, stream>>>(out_b, out_p, tab, ids_ws);
  fused_kernel<<<256, 1024, 0, stream>>>(x, ei, tab, ids_ws, out_x, out_e);
}